// Round 13
// baseline (263.295 us; speedup 1.0000x reference)
//
#include <hip/hip_runtime.h>

#define S_LEN 2048
#define DMODEL 1024
#define NHEADS 16
#define DKH 64

typedef __attribute__((ext_vector_type(8))) short bf16x8;
typedef __attribute__((ext_vector_type(4))) short bf16x4;
typedef __attribute__((ext_vector_type(4))) float f32x4;

#if __has_builtin(__builtin_amdgcn_exp2f)
#define EXP2F(x) __builtin_amdgcn_exp2f(x)
#define QSCALE (0.125f * 1.44269504f)
#else
#define EXP2F(x) __expf(x)
#define QSCALE 0.125f
#endif

static __device__ __forceinline__ short f2bf(float f) {
    unsigned b = __float_as_uint(f);
    b = (b + 0x7FFFu + ((b >> 16) & 1u)) >> 16;   // RNE
    return (short)b;
}

// pack truncated-bf16 of (lo,hi) into one u32
static __device__ __forceinline__ unsigned pktrunc(float lo, float hi) {
#if __has_builtin(__builtin_amdgcn_perm)
    return __builtin_amdgcn_perm(__float_as_uint(hi), __float_as_uint(lo), 0x07060302u);
#else
    return (__float_as_uint(lo) >> 16) | (__float_as_uint(hi) & 0xFFFF0000u);
#endif
}

static __device__ __forceinline__ f32x4 mfma16(bf16x8 a, bf16x8 b, f32x4 c) {
    return __builtin_amdgcn_mfma_f32_16x16x32_bf16(a, b, c, 0, 0, 0);
}

static __device__ __forceinline__ bf16x8 cat44(bf16x4 a, bf16x4 b) {
    bf16x8 r;
    r[0] = a[0]; r[1] = a[1]; r[2] = a[2]; r[3] = a[3];
    r[4] = b[0]; r[5] = b[1]; r[6] = b[2]; r[7] = b[3];
    return r;
}

static __device__ __forceinline__ void glds16(const short* g, short* l) {
    __builtin_amdgcn_global_load_lds(
        (const __attribute__((address_space(1))) void*)g,
        (__attribute__((address_space(3))) void*)l, 16, 0, 0);
}

// ---------------------------------------------------------------------------
// prep: fused fp32->bf16 convert (blocks 0..8191) + mask bit-pack (2048 blocks)
// ---------------------------------------------------------------------------
struct CvtArgs { const float* src[7]; short* dst[7]; };

__global__ __launch_bounds__(256) void prep(CvtArgs a, const int* __restrict__ mask,
                                            unsigned long long* __restrict__ mw) {
    if (blockIdx.x < 8192) {
        const size_t i8 = ((size_t)blockIdx.x * 256 + threadIdx.x) * 8;
        int seg; size_t off;
        if (i8 < ((size_t)12 << 20)) { seg = (int)(i8 >> 22); off = i8 & ((1u << 22) - 1); }
        else { size_t r = i8 - ((size_t)12 << 20); seg = 3 + (int)(r >> 20); off = r & ((1u << 20) - 1); }
        const float* s = a.src[seg] + off;
        float4 x0 = *(const float4*)s, x1 = *(const float4*)(s + 4);
        short o[8];
        o[0] = f2bf(x0.x); o[1] = f2bf(x0.y); o[2] = f2bf(x0.z); o[3] = f2bf(x0.w);
        o[4] = f2bf(x1.x); o[5] = f2bf(x1.y); o[6] = f2bf(x1.z); o[7] = f2bf(x1.w);
        *(uint4*)(a.dst[seg] + off) = *(uint4*)o;
    } else {
        const int wv = ((blockIdx.x - 8192) << 2) + (threadIdx.x >> 6);
        const int lane = threadIdx.x & 63;
        const size_t base = (size_t)wv << 4;
        #pragma unroll 4
        for (int it = 0; it < 16; ++it) {
            const size_t w = base + it;
            const int m = mask[(w << 6) + lane];
            unsigned long long bal = __ballot(m != 0);
            if (lane == 0) mw[w] = bal;
        }
    }
}

// ---------------------------------------------------------------------------
// gemm_bt: C = X @ W^T + bias (bf16), 128x128 tile, BK=64, glds16 staging
// with 8-chunk XOR swizzle. 16 K-steps: 32 MFMA per barrier drain (v11 win:
// gemm<0> 60.4 -> <56us). XCD-cluster tile swizzle.
// MODE 0: z<2 -> bf16 headed [BH][S][DKH] (scaled); z==2 -> TRANSPOSED headed
// kt[bh][d][s].
// ---------------------------------------------------------------------------
struct GemmArgs { const short* X[3]; const short* W[3]; const float* B[3];
                  void* C[3]; float scale[3]; };

template <int MODE>
__global__ __launch_bounds__(256) void gemm_bt(GemmArgs a) {
    __shared__ short Ah[128 * 64];
    __shared__ short Bh[128 * 64];
    const int z = blockIdx.z;
    const short* X = a.X[z];
    const short* W = a.W[z];
    const float* bias = a.B[z];
    const float scl = a.scale[z];

    const int t = threadIdx.x, wid = t >> 6, lane = t & 63;
    const int l15 = lane & 15, lq = lane >> 4;

    // XCD-cluster: lid in [0,256) per z; xcd = lid&7 (256%8==0 so z-invariant)
    const int lid = blockIdx.x + (blockIdx.y << 5);
    const int vm = ((lid & 7) << 2) + ((lid >> 3) & 3);   // [0,32)
    const int vn = lid >> 5;                              // [0,8)

    int m0, n0;
    if (MODE == 0 && z == 2) { m0 = vn << 7; n0 = vm << 7; }
    else                     { m0 = vm << 7; n0 = vn << 7; }
    const int wm = (wid >> 1) << 6, wn = (wid & 1) << 6;

    // staging: sr = row in 8-group, pc = chunk; global chunk pre-swizzled pc^sr
    const int sr = lane >> 3, pc = lane & 7;
    const int scol = (pc ^ sr) << 3;
    const int arow = (wid << 5) + sr;                     // wave's 32-row base
    const short* ag = X + (size_t)(m0 + arow) * 1024 + scol;
    const short* bg = W + (size_t)(n0 + arow) * 1024 + scol;
    short* lA = Ah + (wid << 5) * 64;
    short* lB = Bh + (wid << 5) * 64;

    // read: chunk (kk*4+lq) ^ (row&7); row&7 == l15&7 for all frag rows
    const int key = l15 & 7;
    const int fpk0 = ((lq)     ^ key) << 3;
    const int fpk1 = ((lq + 4) ^ key) << 3;

    f32x4 acc[4][4] = {};

    for (int k0 = 0; k0 < 1024; k0 += 64) {
        __syncthreads();
        glds16(ag,             lA);
        glds16(ag +  8 * 1024, lA +  8 * 64);
        glds16(ag + 16 * 1024, lA + 16 * 64);
        glds16(ag + 24 * 1024, lA + 24 * 64);
        glds16(bg,             lB);
        glds16(bg +  8 * 1024, lB +  8 * 64);
        glds16(bg + 16 * 1024, lB + 16 * 64);
        glds16(bg + 24 * 1024, lB + 24 * 64);
        ag += 64; bg += 64;
        __syncthreads();

        #pragma unroll
        for (int kk = 0; kk < 2; ++kk) {
            const int fp = kk ? fpk1 : fpk0;
            bf16x8 af[4], bfr[4];
            #pragma unroll
            for (int i = 0; i < 4; ++i)
                af[i] = *(const bf16x8*)&Ah[(wm + i * 16 + l15) * 64 + fp];
            #pragma unroll
            for (int j = 0; j < 4; ++j)
                bfr[j] = *(const bf16x8*)&Bh[(wn + j * 16 + l15) * 64 + fp];
            #pragma unroll
            for (int i = 0; i < 4; ++i)
                #pragma unroll
                for (int j = 0; j < 4; ++j)
                    acc[i][j] = mfma16(af[i], bfr[j], acc[i][j]);
        }
    }

    if (MODE == 0 && z == 2) {
        // transposed headed write: kt[(b*16+h)*64+d][s], o = m-row feature
        #pragma unroll
        for (int i = 0; i < 4; ++i) {
            #pragma unroll
            for (int r = 0; r < 4; ++r) {
                const int o = m0 + wm + i * 16 + (lq << 2) + r;
                const float bo_ = bias[o];
                const int h = o >> 6, d = o & 63;
                #pragma unroll
                for (int j = 0; j < 4; ++j) {
                    const int n = n0 + wn + j * 16 + l15;
                    const int bb = n >> 11, s = n & 2047;
                    ((short*)a.C[2])[(((size_t)((bb * 16 + h) << 6) + d) << 11) + s] =
                        f2bf(acc[i][j][r] + bo_);
                }
            }
        }
        return;
    }

    #pragma unroll
    for (int j = 0; j < 4; ++j) {
        const int n = n0 + wn + j * 16 + l15;
        const float bn = bias[n];
        #pragma unroll
        for (int i = 0; i < 4; ++i) {
            const int mbase = m0 + wm + i * 16 + (lq << 2);
            #pragma unroll
            for (int r = 0; r < 4; ++r) {
                const float val = (acc[i][j][r] + bn) * scl;
                const int m = mbase + r;
                if (MODE == 0) {
                    const int b = m >> 11, s = m & 2047, h = n >> 6, d = n & 63;
                    ((short*)a.C[z])[((((size_t)(b * 16 + h)) << 11) + s) * 64 + d] = f2bf(val);
                } else {
                    ((float*)a.C[z])[((size_t)m << 10) + n] = val;
                }
            }
        }
    }
}

// ---------------------------------------------------------------------------
// gemm1f: out = ((O0+O1)/(l0+l1)) @ Wo^T + bo, fp32 out — combine FUSED into
// the A-staging (kills the combine kernel + its 25MB attr round-trip).
// BK=64, one head h per K-step. invl[h][row] built once in LDS (8 KB).
// A is T14 reg-staged: loads for step k+1 issue AFTER sync2 of step k (VGPR
// dest -> no LDS-DMA alias drain, the v2/v3/v7 killer), consumed after next
// sync1 -> latency hidden under step k's MFMAs. Staging math is bit-identical
// to combine: (o0+o1)*invl in fp32, f2bf RNE. LDS write reproduces the glds16
// swizzle: thread (sr,pc) writes physical chunk pc of row==sr (mod 8) holding
// logical chunk pc^sr. B stays glds16. 128x64 tiles, grid (32,16), XCD swz.
// ---------------------------------------------------------------------------
__global__ __launch_bounds__(256) void gemm1f(const short* __restrict__ Op,
                                              const float* __restrict__ lp,
                                              const short* __restrict__ W,
                                              const float* __restrict__ bias,
                                              float* __restrict__ C) {
    __shared__ short Ah[128 * 64];
    __shared__ short Bh[64 * 64];
    __shared__ float invl[16][128];

    const int t = threadIdx.x, wid = t >> 6, lane = t & 63;
    const int l15 = lane & 15, lq = lane >> 4;

    const int lid = blockIdx.x + (blockIdx.y << 5);       // [0,512)
    const int vm = ((lid & 7) << 2) + ((lid >> 3) & 3);   // [0,32)
    const int vn = lid >> 5;                              // [0,16)
    const int m0 = vm << 7, n0 = vn << 6;
    const int wm = (wid >> 1) << 6, wn = (wid & 1) << 5;

    const int bb = m0 >> 11;             // batch (panels don't straddle: 128|2048)
    const int srow0 = m0 & 2047;

    // invl table: 2048 entries / 256 threads = 8 each
    #pragma unroll
    for (int e = 0; e < 8; ++e) {
        const int idx = (e << 8) + t;
        const int h = idx >> 7, rr = idx & 127;
        const size_t lr0 = ((size_t)(bb * 16 + h)) * 2048 + srow0 + rr;
        invl[h][rr] = 1.f / (lp[lr0] + lp[lr0 + (size_t)32 * 2048]);
    }

    const int sr = lane >> 3, pc = lane & 7;
    const int scol = (pc ^ sr) << 3;                      // logical d-chunk [0,64)
    const int arow = (wid << 5) + sr;                     // local row, +8 per rr
    const int srow = srow0 + arow;
    const short* bg = W + (size_t)(n0 + (wid << 4) + sr) * 1024 + scol;
    short* lA = Ah + ((wid << 5) + sr) * 64 + (pc << 3);
    short* lB = Bh + (wid << 4) * 64;

    const int key = l15 & 7;
    const int fpk0 = ((lq)     ^ key) << 3;
    const int fpk1 = ((lq + 4) ^ key) << 3;

    f32x4 acc[4][2] = {};
    uint4 o0[4], o1[4];

    auto issueA = [&](int h) {
        #pragma unroll
        for (int rr = 0; rr < 4; ++rr) {
            const size_t row = (((size_t)(bb * 16 + h)) << 11) + srow + (rr << 3);
            o0[rr] = *(const uint4*)(Op + (row << 6) + scol);
            o1[rr] = *(const uint4*)(Op + ((row + ((size_t)32 << 11)) << 6) + scol);
        }
    };

    issueA(0);

    for (int h = 0; h < 16; ++h) {
        __syncthreads();            // prev reads done; iter 0: invl table ready
        #pragma unroll
        for (int rr = 0; rr < 4; ++rr) {
            const float v = invl[h][arow + (rr << 3)];
            const unsigned* a0 = (const unsigned*)&o0[rr];
            const unsigned* a1 = (const unsigned*)&o1[rr];
            short o[8];
            #pragma unroll
            for (int i = 0; i < 4; ++i) {
                const float x0 = __uint_as_float(a0[i] << 16);
                const float x1 = __uint_as_float(a0[i] & 0xFFFF0000u);
                const float y0 = __uint_as_float(a1[i] << 16);
                const float y1 = __uint_as_float(a1[i] & 0xFFFF0000u);
                o[2 * i + 0] = f2bf((x0 + y0) * v);
                o[2 * i + 1] = f2bf((x1 + y1) * v);
            }
            *(uint4*)(lA + (rr << 3) * 64) = *(uint4*)o;
        }
        glds16(bg, lB);
        glds16(bg + 8 * 1024, lB + 8 * 64);
        bg += 64;
        __syncthreads();            // A writes + B dma visible
        if (h < 15) issueA(h + 1);  // VGPR loads fly across compute + next sync

        #pragma unroll
        for (int kk = 0; kk < 2; ++kk) {
            const int fp = kk ? fpk1 : fpk0;
            bf16x8 af[4], bfr[2];
            #pragma unroll
            for (int i = 0; i < 4; ++i)
                af[i] = *(const bf16x8*)&Ah[(wm + i * 16 + l15) * 64 + fp];
            #pragma unroll
            for (int j = 0; j < 2; ++j)
                bfr[j] = *(const bf16x8*)&Bh[(wn + j * 16 + l15) * 64 + fp];
            #pragma unroll
            for (int i = 0; i < 4; ++i)
                #pragma unroll
                for (int j = 0; j < 2; ++j)
                    acc[i][j] = mfma16(af[i], bfr[j], acc[i][j]);
        }
    }

    #pragma unroll
    for (int j = 0; j < 2; ++j) {
        const int n = n0 + wn + j * 16 + l15;
        const float bn = bias[n];
        #pragma unroll
        for (int i = 0; i < 4; ++i) {
            const int mbase = m0 + wm + i * 16 + (lq << 2);
            #pragma unroll
            for (int r = 0; r < 4; ++r)
                C[((size_t)(mbase + r) << 10) + n] = acc[i][j][r] + bn;
        }
    }
}

// ---------------------------------------------------------------------------
// attn4: transposed-S flash attention (reference K/V swap). S^T = V@Q^T via
// 16x16x32 (C-layout col=i=l15, row=j=lq*4+r) -> exp'd scores ARE the
// A-fragments of PV MFMAs (zero P LDS traffic). l via MFMA against all-ones B.
// V and kt staged in LDS with 16B XOR swizzle. j-split z=2; partials merged
// by gemm1f. Block: 4 waves x 32 i-rows = 128 rows; grid (16, 32, 2).
// K32 PV/lsum (v6). At its structural floor (~56.5us): pipelining, occupancy,
// KVBLK=128, XCD-cluster all closed (v2-v9).
// ---------------------------------------------------------------------------
__global__ __launch_bounds__(256, 4) void attn4(
    const short* __restrict__ Qh, const short* __restrict__ Vh,
    const short* __restrict__ Kt, const unsigned long long* __restrict__ MW,
    short* __restrict__ Opart, float* __restrict__ lpart)
{
    __shared__ short Vs[64 * 64];    // [j][d], 16B-chunk xor-swizzled
    __shared__ short Ks[64 * 64];    // [d][j], 16B-chunk xor-swizzled

    const int t = threadIdx.x, wid = t >> 6, lane = t & 63;
    const int l15 = lane & 15, lq = lane >> 4;
    const int bh = blockIdx.y, b = bh >> 4;
    const int z = blockIdx.z;
    const int ib = (blockIdx.x << 7) + (wid << 5);
    const int jbase = z << 10;

    // Q B-frags: B[n=i][k=d], rows ib + it*16 + l15
    bf16x8 qf[2][2];
    #pragma unroll
    for (int it = 0; it < 2; ++it) {
        const short* qp = Qh + ((size_t)bh * 2048 + ib + it * 16 + l15) * 64 + (lq << 3);
        qf[it][0] = *(const bf16x8*)qp;
        qf[it][1] = *(const bf16x8*)(qp + 32);
    }

    // staging: each wave stages 16 rows of V and 16 d-rows of Kt
    const int sr = lane >> 3, pc = lane & 7;
    const int lc = pc ^ sr;                      // logical 16B chunk
    const int wr = wid << 4;
    const short* vsrc = Vh + (size_t)bh * 131072 + (size_t)(jbase + wr + sr) * 64 + (lc << 3);
    const short* ksrc = Kt + (size_t)bh * 131072 + (size_t)(wr + sr) * 2048 + jbase + (lc << 3);
    short* vdst = Vs + (wr << 6);
    short* kdst = Ks + (wr << 6);

    const unsigned long long* mwp0 = MW + ((size_t)b * 2048 + ib + l15) * 32 + (z << 4);
    const unsigned long long* mwp1 = mwp0 + (size_t)16 * 32;

    const int x7 = l15 & 7;
    int voff[2], koff[4];
    #pragma unroll
    for (int p = 0; p < 2; ++p) voff[p] = (((p << 2) + lq) ^ x7) << 3;
    #pragma unroll
    for (int jt = 0; jt < 4; ++jt) {
        const int c8 = (jt << 2) + lq;           // logical 8B chunk
        koff[jt] = (((c8 >> 1) ^ x7) << 3) + ((c8 & 1) << 2);
    }

    f32x4 O[2][4] = {};
    f32x4 lsum[2] = {};
    bf16x8 ones8;
    #pragma unroll
    for (int e = 0; e < 8; ++e) ones8[e] = (short)0x3F80;

    for (int jc = 0; jc < 16; ++jc) {
        __syncthreads();
        glds16(vsrc, vdst);
        glds16(vsrc + 512, vdst + 512);
        glds16(ksrc, kdst);
        glds16(ksrc + 8 * 2048, kdst + 512);
        vsrc += 4096; ksrc += 64;

        uint2 mword[2];
        mword[0] = *(const uint2*)(mwp0 + jc);
        mword[1] = *(const uint2*)(mwp1 + jc);
        __syncthreads();

        // V A-frags: A[m=j][k=d]
        bf16x8 vf[4][2];
        #pragma unroll
        for (int jt = 0; jt < 4; ++jt) {
            const short* vp = &Vs[((jt << 4) + l15) << 6];
            vf[jt][0] = *(const bf16x8*)(vp + voff[0]);
            vf[jt][1] = *(const bf16x8*)(vp + voff[1]);
        }

        // S^T tiles -> exp -> packed K32 P A-frags (registers), l via ones-MFMA
        bf16x8 pa[2][2];                         // [it][b2]: concat of jt=2b2,2b2+1
        #pragma unroll
        for (int it = 0; it < 2; ++it) {
            const unsigned wx = mword[it].x, wy = mword[it].y;
            #pragma unroll
            for (int b2 = 0; b2 < 2; ++b2) {
                uint4 uu4;
                unsigned* uw = (unsigned*)&uu4;
                #pragma unroll
                for (int h = 0; h < 2; ++h) {
                    const int jt = (b2 << 1) + h;
                    f32x4 sc = {};
                    sc = mfma16(vf[jt][0], qf[it][0], sc);
                    sc = mfma16(vf[jt][1], qf[it][1], sc);
                    const unsigned w32 = (jt < 2) ? wx : wy;
                    float p[4];
                    #pragma unroll
                    for (int r = 0; r < 4; ++r) {
                        const unsigned bit = (w32 >> (((jt & 1) << 4) + (lq << 2) + r)) & 1u;
                        const float e = EXP2F(sc[r]);
                        p[r] = bit ? e : 0.f;
                    }
                    uw[(h << 1) + 0] = pktrunc(p[0], p[1]);
                    uw[(h << 1) + 1] = pktrunc(p[2], p[3]);
                }
                pa[it][b2] = __builtin_bit_cast(bf16x8, uu4);
                lsum[it] = mfma16(pa[it][b2], ones8, lsum[it]);
            }
        }

        // O += P @ K : B[n=d][k=j] = concat of the two b64 Ks reads per pair
        #pragma unroll
        for (int dt = 0; dt < 4; ++dt) {
            const short* kp = &Ks[((dt << 4) + l15) << 6];
            #pragma unroll
            for (int b2 = 0; b2 < 2; ++b2) {
                const bf16x4 k0 = *(const bf16x4*)(kp + koff[(b2 << 1) + 0]);
                const bf16x4 k1 = *(const bf16x4*)(kp + koff[(b2 << 1) + 1]);
                const bf16x8 kk = cat44(k0, k1);
                O[0][dt] = mfma16(pa[0][b2], kk, O[0][dt]);
                O[1][dt] = mfma16(pa[1][b2], kk, O[1][dt]);
            }
        }
    }

    // epilogue: rows i = lq*4+r; cols d = dt*16+l15; l duplicated across l15
    const size_t zb = (size_t)((z << 5) + bh) * 2048;
    #pragma unroll
    for (int it = 0; it < 2; ++it) {
        const int rb = ib + (it << 4) + (lq << 2);
        if (l15 == 0) {
            #pragma unroll
            for (int r = 0; r < 4; ++r)
                lpart[zb + rb + r] = lsum[it][r];
        }
        #pragma unroll
        for (int dt = 0; dt < 4; ++dt)
            #pragma unroll
            for (int r = 0; r < 4; ++r)
                Opart[(zb + rb + r) * 64 + (dt << 4) + l15] = f2bf(O[it][dt][r]);
    }
}

// ---------------------------------------------------------------------------
extern "C" void kernel_launch(void* const* d_in, const int* in_sizes, int n_in,
                              void* d_out, int out_size, void* d_ws, size_t ws_size,
                              hipStream_t stream) {
    const float* value = (const float*)d_in[0];
    const float* key   = (const float*)d_in[1];
    const float* query = (const float*)d_in[2];
    const int*   mask  = (const int*)d_in[3];
    const float* bv = (const float*)d_in[5];
    const float* bk = (const float*)d_in[7];
    const float* bq = (const float*)d_in[9];
    const float* bo = (const float*)d_in[11];
    float* out = (float*)d_out;

    const size_t M1 = (size_t)1 << 20, M4 = (size_t)1 << 22;
    short* ws = (short*)d_ws;
    short* Xq = ws;
    short* Xk = ws + M4;                  // reused as Opart after proj (2*M4)
    short* Xv = ws + 2 * M4;
    short* Wc0 = ws + 3 * M4;             // reused as lpart after proj
    short* Wc1 = Wc0 + M1;
    short* Wc2 = Wc1 + M1;
    short* Wc3 = Wc2 + M1;
    short* qh = ws + 4 * M4;
    short* kt = ws + 5 * M4;
    short* vh = ws + 6 * M4;
    unsigned long long* maskw = (unsigned long long*)(ws + 7 * M4);
    short* Opart = Xk;
    float* lpart = (float*)Wc0;

    CvtArgs cv;
    cv.src[0] = query; cv.dst[0] = Xq;
    cv.src[1] = key;   cv.dst[1] = Xk;
    cv.src[2] = value; cv.dst[2] = Xv;
    cv.src[3] = (const float*)d_in[8];  cv.dst[3] = Wc0;  // Wq
    cv.src[4] = (const float*)d_in[6];  cv.dst[4] = Wc1;  // Wk
    cv.src[5] = (const float*)d_in[4];  cv.dst[5] = Wc2;  // Wv
    cv.src[6] = (const float*)d_in[10]; cv.dst[6] = Wc3;  // Wo
    prep<<<10240, 256, 0, stream>>>(cv, mask, maskw);

    GemmArgs g1;
    g1.X[0] = Xq;  g1.W[0] = Wc0; g1.B[0] = bq; g1.C[0] = qh; g1.scale[0] = QSCALE;
    g1.X[1] = Xv;  g1.W[1] = Wc2; g1.B[1] = bv; g1.C[1] = vh; g1.scale[1] = 1.f;
    g1.X[2] = Wc1; g1.W[2] = Xk;  g1.B[2] = bk; g1.C[2] = kt; g1.scale[2] = 1.f;  // transposed K
    gemm_bt<0><<<dim3(32, 8, 3), 256, 0, stream>>>(g1);

    attn4<<<dim3(16, 32, 2), 256, 0, stream>>>(qh, vh, kt, maskw, Opart, lpart);

    gemm1f<<<dim3(32, 16), 256, 0, stream>>>(Opart, lpart, Wc3, bo, out);
}

// Round 14
// 256.260 us; speedup vs baseline: 1.0275x; 1.0275x over previous
//
#include <hip/hip_runtime.h>

#define S_LEN 2048
#define DMODEL 1024
#define NHEADS 16
#define DKH 64

typedef __attribute__((ext_vector_type(8))) short bf16x8;
typedef __attribute__((ext_vector_type(4))) short bf16x4;
typedef __attribute__((ext_vector_type(4))) float f32x4;

#if __has_builtin(__builtin_amdgcn_exp2f)
#define EXP2F(x) __builtin_amdgcn_exp2f(x)
#define QSCALE (0.125f * 1.44269504f)
#else
#define EXP2F(x) __expf(x)
#define QSCALE 0.125f
#endif

static __device__ __forceinline__ short f2bf(float f) {
    unsigned b = __float_as_uint(f);
    b = (b + 0x7FFFu + ((b >> 16) & 1u)) >> 16;   // RNE
    return (short)b;
}

// pack truncated-bf16 of (lo,hi) into one u32
static __device__ __forceinline__ unsigned pktrunc(float lo, float hi) {
#if __has_builtin(__builtin_amdgcn_perm)
    return __builtin_amdgcn_perm(__float_as_uint(hi), __float_as_uint(lo), 0x07060302u);
#else
    return (__float_as_uint(lo) >> 16) | (__float_as_uint(hi) & 0xFFFF0000u);
#endif
}

static __device__ __forceinline__ f32x4 mfma16(bf16x8 a, bf16x8 b, f32x4 c) {
    return __builtin_amdgcn_mfma_f32_16x16x32_bf16(a, b, c, 0, 0, 0);
}

static __device__ __forceinline__ bf16x8 cat44(bf16x4 a, bf16x4 b) {
    bf16x8 r;
    r[0] = a[0]; r[1] = a[1]; r[2] = a[2]; r[3] = a[3];
    r[4] = b[0]; r[5] = b[1]; r[6] = b[2]; r[7] = b[3];
    return r;
}

static __device__ __forceinline__ void glds16(const short* g, short* l) {
    __builtin_amdgcn_global_load_lds(
        (const __attribute__((address_space(1))) void*)g,
        (__attribute__((address_space(3))) void*)l, 16, 0, 0);
}

// ---------------------------------------------------------------------------
// prep: fused fp32->bf16 convert (blocks 0..8191) + mask bit-pack (2048 blocks)
// ---------------------------------------------------------------------------
struct CvtArgs { const float* src[7]; short* dst[7]; };

__global__ __launch_bounds__(256) void prep(CvtArgs a, const int* __restrict__ mask,
                                            unsigned long long* __restrict__ mw) {
    if (blockIdx.x < 8192) {
        const size_t i8 = ((size_t)blockIdx.x * 256 + threadIdx.x) * 8;
        int seg; size_t off;
        if (i8 < ((size_t)12 << 20)) { seg = (int)(i8 >> 22); off = i8 & ((1u << 22) - 1); }
        else { size_t r = i8 - ((size_t)12 << 20); seg = 3 + (int)(r >> 20); off = r & ((1u << 20) - 1); }
        const float* s = a.src[seg] + off;
        float4 x0 = *(const float4*)s, x1 = *(const float4*)(s + 4);
        short o[8];
        o[0] = f2bf(x0.x); o[1] = f2bf(x0.y); o[2] = f2bf(x0.z); o[3] = f2bf(x0.w);
        o[4] = f2bf(x1.x); o[5] = f2bf(x1.y); o[6] = f2bf(x1.z); o[7] = f2bf(x1.w);
        *(uint4*)(a.dst[seg] + off) = *(uint4*)o;
    } else {
        const int wv = ((blockIdx.x - 8192) << 2) + (threadIdx.x >> 6);
        const int lane = threadIdx.x & 63;
        const size_t base = (size_t)wv << 4;
        #pragma unroll 4
        for (int it = 0; it < 16; ++it) {
            const size_t w = base + it;
            const int m = mask[(w << 6) + lane];
            unsigned long long bal = __ballot(m != 0);
            if (lane == 0) mw[w] = bal;
        }
    }
}

// ---------------------------------------------------------------------------
// gemm_bt: C = X @ W^T + bias (bf16), 128x128 tile, BK=64, glds16 staging
// with 8-chunk XOR swizzle (stored chunk = pc^sr via pre-swizzled global
// src; read key = l15&7; 2-way bank aliasing free). 16 K-steps: 32 MFMA per
// barrier drain (v11 win: gemm<0> 60.4 -> <56us). XCD-cluster tile swizzle.
// MODE 0: z<2 -> bf16 headed [BH][S][DKH] (scaled); z==2 -> TRANSPOSED headed
// kt[bh][d][s].
// ---------------------------------------------------------------------------
struct GemmArgs { const short* X[3]; const short* W[3]; const float* B[3];
                  void* C[3]; float scale[3]; };

template <int MODE>
__global__ __launch_bounds__(256) void gemm_bt(GemmArgs a) {
    __shared__ short Ah[128 * 64];
    __shared__ short Bh[128 * 64];
    const int z = blockIdx.z;
    const short* X = a.X[z];
    const short* W = a.W[z];
    const float* bias = a.B[z];
    const float scl = a.scale[z];

    const int t = threadIdx.x, wid = t >> 6, lane = t & 63;
    const int l15 = lane & 15, lq = lane >> 4;

    // XCD-cluster: lid in [0,256) per z; xcd = lid&7 (256%8==0 so z-invariant)
    const int lid = blockIdx.x + (blockIdx.y << 5);
    const int vm = ((lid & 7) << 2) + ((lid >> 3) & 3);   // [0,32)
    const int vn = lid >> 5;                              // [0,8)

    int m0, n0;
    if (MODE == 0 && z == 2) { m0 = vn << 7; n0 = vm << 7; }
    else                     { m0 = vm << 7; n0 = vn << 7; }
    const int wm = (wid >> 1) << 6, wn = (wid & 1) << 6;

    // staging: sr = row in 8-group, pc = chunk; global chunk pre-swizzled pc^sr
    const int sr = lane >> 3, pc = lane & 7;
    const int scol = (pc ^ sr) << 3;
    const int arow = (wid << 5) + sr;                     // wave's 32-row base
    const short* ag = X + (size_t)(m0 + arow) * 1024 + scol;
    const short* bg = W + (size_t)(n0 + arow) * 1024 + scol;
    short* lA = Ah + (wid << 5) * 64;
    short* lB = Bh + (wid << 5) * 64;

    // read: chunk (kk*4+lq) ^ (row&7); row&7 == l15&7 for all frag rows
    const int key = l15 & 7;
    const int fpk0 = ((lq)     ^ key) << 3;
    const int fpk1 = ((lq + 4) ^ key) << 3;

    f32x4 acc[4][4] = {};

    for (int k0 = 0; k0 < 1024; k0 += 64) {
        __syncthreads();
        glds16(ag,             lA);
        glds16(ag +  8 * 1024, lA +  8 * 64);
        glds16(ag + 16 * 1024, lA + 16 * 64);
        glds16(ag + 24 * 1024, lA + 24 * 64);
        glds16(bg,             lB);
        glds16(bg +  8 * 1024, lB +  8 * 64);
        glds16(bg + 16 * 1024, lB + 16 * 64);
        glds16(bg + 24 * 1024, lB + 24 * 64);
        ag += 64; bg += 64;
        __syncthreads();

        #pragma unroll
        for (int kk = 0; kk < 2; ++kk) {
            const int fp = kk ? fpk1 : fpk0;
            bf16x8 af[4], bfr[4];
            #pragma unroll
            for (int i = 0; i < 4; ++i)
                af[i] = *(const bf16x8*)&Ah[(wm + i * 16 + l15) * 64 + fp];
            #pragma unroll
            for (int j = 0; j < 4; ++j)
                bfr[j] = *(const bf16x8*)&Bh[(wn + j * 16 + l15) * 64 + fp];
            #pragma unroll
            for (int i = 0; i < 4; ++i)
                #pragma unroll
                for (int j = 0; j < 4; ++j)
                    acc[i][j] = mfma16(af[i], bfr[j], acc[i][j]);
        }
    }

    if (MODE == 0 && z == 2) {
        // transposed headed write: kt[(b*16+h)*64+d][s], o = m-row feature
        #pragma unroll
        for (int i = 0; i < 4; ++i) {
            #pragma unroll
            for (int r = 0; r < 4; ++r) {
                const int o = m0 + wm + i * 16 + (lq << 2) + r;
                const float bo_ = bias[o];
                const int h = o >> 6, d = o & 63;
                #pragma unroll
                for (int j = 0; j < 4; ++j) {
                    const int n = n0 + wn + j * 16 + l15;
                    const int bb = n >> 11, s = n & 2047;
                    ((short*)a.C[2])[(((size_t)((bb * 16 + h) << 6) + d) << 11) + s] =
                        f2bf(acc[i][j][r] + bo_);
                }
            }
        }
        return;
    }

    #pragma unroll
    for (int j = 0; j < 4; ++j) {
        const int n = n0 + wn + j * 16 + l15;
        const float bn = bias[n];
        #pragma unroll
        for (int i = 0; i < 4; ++i) {
            const int mbase = m0 + wm + i * 16 + (lq << 2);
            #pragma unroll
            for (int r = 0; r < 4; ++r) {
                const float val = (acc[i][j][r] + bn) * scl;
                const int m = mbase + r;
                if (MODE == 0) {
                    const int b = m >> 11, s = m & 2047, h = n >> 6, d = n & 63;
                    ((short*)a.C[z])[((((size_t)(b * 16 + h)) << 11) + s) * 64 + d] = f2bf(val);
                } else {
                    ((float*)a.C[z])[((size_t)m << 10) + n] = val;
                }
            }
        }
    }
}

// ---------------------------------------------------------------------------
// gemm1_64: out = attr @ Wo^T + bo, fp32 out. 128x64 tiles, grid (32,16) =
// 512 blocks = 2 blocks/CU. BK=64: 16 K-steps, per step 6 glds16 +
// 2x(6 ds_read + 8 MFMA). LDS 24KB. XCD swizzle.
// (v12 lesson: fusing combine's VALU math into this staging regresses —
// keep the BW-bound combine separate.)
// ---------------------------------------------------------------------------
__global__ __launch_bounds__(256) void gemm1_64(const short* __restrict__ X,
                                                const short* __restrict__ W,
                                                const float* __restrict__ bias,
                                                float* __restrict__ C) {
    __shared__ short Ah[128 * 64];
    __shared__ short Bh[64 * 64];

    const int t = threadIdx.x, wid = t >> 6, lane = t & 63;
    const int l15 = lane & 15, lq = lane >> 4;

    const int lid = blockIdx.x + (blockIdx.y << 5);       // [0,512)
    const int vm = ((lid & 7) << 2) + ((lid >> 3) & 3);   // [0,32)
    const int vn = lid >> 5;                              // [0,16)
    const int m0 = vm << 7, n0 = vn << 6;
    const int wm = (wid >> 1) << 6, wn = (wid & 1) << 5;

    const int sr = lane >> 3, pc = lane & 7;
    const int scol = (pc ^ sr) << 3;
    const short* ag = X + (size_t)(m0 + (wid << 5) + sr) * 1024 + scol;
    const short* bg = W + (size_t)(n0 + (wid << 4) + sr) * 1024 + scol;
    short* lA = Ah + (wid << 5) * 64;
    short* lB = Bh + (wid << 4) * 64;

    const int key = l15 & 7;
    const int fpk0 = ((lq)     ^ key) << 3;
    const int fpk1 = ((lq + 4) ^ key) << 3;

    f32x4 acc[4][2] = {};

    for (int k0 = 0; k0 < 1024; k0 += 64) {
        __syncthreads();
        glds16(ag,             lA);
        glds16(ag +  8 * 1024, lA +  8 * 64);
        glds16(ag + 16 * 1024, lA + 16 * 64);
        glds16(ag + 24 * 1024, lA + 24 * 64);
        glds16(bg,             lB);
        glds16(bg +  8 * 1024, lB +  8 * 64);
        ag += 64; bg += 64;
        __syncthreads();

        #pragma unroll
        for (int kk = 0; kk < 2; ++kk) {
            const int fp = kk ? fpk1 : fpk0;
            bf16x8 af[4], bfr[2];
            #pragma unroll
            for (int i = 0; i < 4; ++i)
                af[i] = *(const bf16x8*)&Ah[(wm + i * 16 + l15) * 64 + fp];
            #pragma unroll
            for (int j = 0; j < 2; ++j)
                bfr[j] = *(const bf16x8*)&Bh[(wn + j * 16 + l15) * 64 + fp];
            #pragma unroll
            for (int i = 0; i < 4; ++i)
                #pragma unroll
                for (int j = 0; j < 2; ++j)
                    acc[i][j] = mfma16(af[i], bfr[j], acc[i][j]);
        }
    }

    #pragma unroll
    for (int j = 0; j < 2; ++j) {
        const int n = n0 + wn + j * 16 + l15;
        const float bn = bias[n];
        #pragma unroll
        for (int i = 0; i < 4; ++i) {
            const int mbase = m0 + wm + i * 16 + (lq << 2);
            #pragma unroll
            for (int r = 0; r < 4; ++r)
                C[((size_t)(mbase + r) << 10) + n] = acc[i][j][r] + bn;
        }
    }
}

// ---------------------------------------------------------------------------
// attn4: transposed-S flash attention (reference K/V swap). S^T = V@Q^T via
// 16x16x32 (C-layout col=i=l15, row=j=lq*4+r) -> exp'd scores ARE the
// A-fragments of PV MFMAs (zero P LDS traffic). l via MFMA against all-ones B.
// V and kt staged in LDS with 16B XOR swizzle. j-split z=2; partials merged
// by `combine`. Block: 4 waves x 32 i-rows = 128 rows; grid (16, 32, 2).
// K32 PV/lsum (v6). At its structural floor (~56.5us): pipelining (v2/v3/v7),
// occupancy (v4/v5), KVBLK=128 (v8), XCD-cluster (v9), fusion (v12) all
// closed. Floor = VALU/exp chain + per-jc sync at 4 blocks/CU.
// ---------------------------------------------------------------------------
__global__ __launch_bounds__(256, 4) void attn4(
    const short* __restrict__ Qh, const short* __restrict__ Vh,
    const short* __restrict__ Kt, const unsigned long long* __restrict__ MW,
    short* __restrict__ Opart, float* __restrict__ lpart)
{
    __shared__ short Vs[64 * 64];    // [j][d], 16B-chunk xor-swizzled
    __shared__ short Ks[64 * 64];    // [d][j], 16B-chunk xor-swizzled

    const int t = threadIdx.x, wid = t >> 6, lane = t & 63;
    const int l15 = lane & 15, lq = lane >> 4;
    const int bh = blockIdx.y, b = bh >> 4;
    const int z = blockIdx.z;
    const int ib = (blockIdx.x << 7) + (wid << 5);
    const int jbase = z << 10;

    // Q B-frags: B[n=i][k=d], rows ib + it*16 + l15
    bf16x8 qf[2][2];
    #pragma unroll
    for (int it = 0; it < 2; ++it) {
        const short* qp = Qh + ((size_t)bh * 2048 + ib + it * 16 + l15) * 64 + (lq << 3);
        qf[it][0] = *(const bf16x8*)qp;
        qf[it][1] = *(const bf16x8*)(qp + 32);
    }

    // staging: each wave stages 16 rows of V and 16 d-rows of Kt
    const int sr = lane >> 3, pc = lane & 7;
    const int lc = pc ^ sr;                      // logical 16B chunk
    const int wr = wid << 4;
    const short* vsrc = Vh + (size_t)bh * 131072 + (size_t)(jbase + wr + sr) * 64 + (lc << 3);
    const short* ksrc = Kt + (size_t)bh * 131072 + (size_t)(wr + sr) * 2048 + jbase + (lc << 3);
    short* vdst = Vs + (wr << 6);
    short* kdst = Ks + (wr << 6);

    const unsigned long long* mwp0 = MW + ((size_t)b * 2048 + ib + l15) * 32 + (z << 4);
    const unsigned long long* mwp1 = mwp0 + (size_t)16 * 32;

    const int x7 = l15 & 7;
    int voff[2], koff[4];
    #pragma unroll
    for (int p = 0; p < 2; ++p) voff[p] = (((p << 2) + lq) ^ x7) << 3;
    #pragma unroll
    for (int jt = 0; jt < 4; ++jt) {
        const int c8 = (jt << 2) + lq;           // logical 8B chunk
        koff[jt] = (((c8 >> 1) ^ x7) << 3) + ((c8 & 1) << 2);
    }

    f32x4 O[2][4] = {};
    f32x4 lsum[2] = {};
    bf16x8 ones8;
    #pragma unroll
    for (int e = 0; e < 8; ++e) ones8[e] = (short)0x3F80;

    for (int jc = 0; jc < 16; ++jc) {
        __syncthreads();
        glds16(vsrc, vdst);
        glds16(vsrc + 512, vdst + 512);
        glds16(ksrc, kdst);
        glds16(ksrc + 8 * 2048, kdst + 512);
        vsrc += 4096; ksrc += 64;

        uint2 mword[2];
        mword[0] = *(const uint2*)(mwp0 + jc);
        mword[1] = *(const uint2*)(mwp1 + jc);
        __syncthreads();

        // V A-frags: A[m=j][k=d]
        bf16x8 vf[4][2];
        #pragma unroll
        for (int jt = 0; jt < 4; ++jt) {
            const short* vp = &Vs[((jt << 4) + l15) << 6];
            vf[jt][0] = *(const bf16x8*)(vp + voff[0]);
            vf[jt][1] = *(const bf16x8*)(vp + voff[1]);
        }

        // S^T tiles -> exp -> packed K32 P A-frags (registers), l via ones-MFMA
        bf16x8 pa[2][2];                         // [it][b2]: concat of jt=2b2,2b2+1
        #pragma unroll
        for (int it = 0; it < 2; ++it) {
            const unsigned wx = mword[it].x, wy = mword[it].y;
            #pragma unroll
            for (int b2 = 0; b2 < 2; ++b2) {
                uint4 uu4;
                unsigned* uw = (unsigned*)&uu4;
                #pragma unroll
                for (int h = 0; h < 2; ++h) {
                    const int jt = (b2 << 1) + h;
                    f32x4 sc = {};
                    sc = mfma16(vf[jt][0], qf[it][0], sc);
                    sc = mfma16(vf[jt][1], qf[it][1], sc);
                    const unsigned w32 = (jt < 2) ? wx : wy;
                    float p[4];
                    #pragma unroll
                    for (int r = 0; r < 4; ++r) {
                        const unsigned bit = (w32 >> (((jt & 1) << 4) + (lq << 2) + r)) & 1u;
                        const float e = EXP2F(sc[r]);
                        p[r] = bit ? e : 0.f;
                    }
                    uw[(h << 1) + 0] = pktrunc(p[0], p[1]);
                    uw[(h << 1) + 1] = pktrunc(p[2], p[3]);
                }
                pa[it][b2] = __builtin_bit_cast(bf16x8, uu4);
                lsum[it] = mfma16(pa[it][b2], ones8, lsum[it]);
            }
        }

        // O += P @ K : B[n=d][k=j] = concat of the two b64 Ks reads per pair
        #pragma unroll
        for (int dt = 0; dt < 4; ++dt) {
            const short* kp = &Ks[((dt << 4) + l15) << 6];
            #pragma unroll
            for (int b2 = 0; b2 < 2; ++b2) {
                const bf16x4 k0 = *(const bf16x4*)(kp + koff[(b2 << 1) + 0]);
                const bf16x4 k1 = *(const bf16x4*)(kp + koff[(b2 << 1) + 1]);
                const bf16x8 kk = cat44(k0, k1);
                O[0][dt] = mfma16(pa[0][b2], kk, O[0][dt]);
                O[1][dt] = mfma16(pa[1][b2], kk, O[1][dt]);
            }
        }
    }

    // epilogue: rows i = lq*4+r; cols d = dt*16+l15; l duplicated across l15
    const size_t zb = (size_t)((z << 5) + bh) * 2048;
    #pragma unroll
    for (int it = 0; it < 2; ++it) {
        const int rb = ib + (it << 4) + (lq << 2);
        if (l15 == 0) {
            #pragma unroll
            for (int r = 0; r < 4; ++r)
                lpart[zb + rb + r] = lsum[it][r];
        }
        #pragma unroll
        for (int dt = 0; dt < 4; ++dt)
            #pragma unroll
            for (int r = 0; r < 4; ++r)
                Opart[(zb + rb + r) * 64 + (dt << 4) + l15] = f2bf(O[it][dt][r]);
    }
}

// ---------------------------------------------------------------------------
// combine: attr[b][s][h*64+d] = (O0+O1)/(l0+l1), bf16 out
// ---------------------------------------------------------------------------
__global__ __launch_bounds__(256) void combine(const short* __restrict__ Op,
                                               const float* __restrict__ lp,
                                               short* __restrict__ attr) {
    const int idx = blockIdx.x * 256 + threadIdx.x;      // 524288 total
    const int d8 = (idx & 7) << 3;
    const int srow = (idx >> 3) & 2047;
    const int bh = idx >> 14, b = bh >> 4, h = bh & 15;
    const size_t r0 = (size_t)bh * 2048 + srow;
    const size_t r1 = r0 + (size_t)32 * 2048;
    uint4 a = *(const uint4*)(Op + r0 * 64 + d8);
    uint4 c = *(const uint4*)(Op + r1 * 64 + d8);
    const float inv = 1.f / (lp[r0] + lp[r1]);
    const unsigned* au = (const unsigned*)&a;
    const unsigned* cu = (const unsigned*)&c;
    short o[8];
    #pragma unroll
    for (int i = 0; i < 4; ++i) {
        const float a0 = __uint_as_float(au[i] << 16);
        const float a1 = __uint_as_float(au[i] & 0xFFFF0000u);
        const float c0 = __uint_as_float(cu[i] << 16);
        const float c1 = __uint_as_float(cu[i] & 0xFFFF0000u);
        o[2 * i + 0] = f2bf((a0 + c0) * inv);
        o[2 * i + 1] = f2bf((a1 + c1) * inv);
    }
    *(uint4*)&attr[((size_t)b * 2048 + srow) * 1024 + (h << 6) + d8] = *(uint4*)o;
}

// ---------------------------------------------------------------------------
extern "C" void kernel_launch(void* const* d_in, const int* in_sizes, int n_in,
                              void* d_out, int out_size, void* d_ws, size_t ws_size,
                              hipStream_t stream) {
    const float* value = (const float*)d_in[0];
    const float* key   = (const float*)d_in[1];
    const float* query = (const float*)d_in[2];
    const int*   mask  = (const int*)d_in[3];
    const float* bv = (const float*)d_in[5];
    const float* bk = (const float*)d_in[7];
    const float* bq = (const float*)d_in[9];
    const float* bo = (const float*)d_in[11];
    float* out = (float*)d_out;

    const size_t M1 = (size_t)1 << 20, M4 = (size_t)1 << 22;
    short* ws = (short*)d_ws;
    short* Xq = ws;                       // reused as attr after proj
    short* Xk = ws + M4;                  // reused as Opart after proj (2*M4)
    short* Xv = ws + 2 * M4;
    short* Wc0 = ws + 3 * M4;             // reused as lpart after proj
    short* Wc1 = Wc0 + M1;
    short* Wc2 = Wc1 + M1;
    short* Wc3 = Wc2 + M1;
    short* qh = ws + 4 * M4;
    short* kt = ws + 5 * M4;
    short* vh = ws + 6 * M4;
    unsigned long long* maskw = (unsigned long long*)(ws + 7 * M4);
    short* attr = Xq;
    short* Opart = Xk;
    float* lpart = (float*)Wc0;

    CvtArgs cv;
    cv.src[0] = query; cv.dst[0] = Xq;
    cv.src[1] = key;   cv.dst[1] = Xk;
    cv.src[2] = value; cv.dst[2] = Xv;
    cv.src[3] = (const float*)d_in[8];  cv.dst[3] = Wc0;  // Wq
    cv.src[4] = (const float*)d_in[6];  cv.dst[4] = Wc1;  // Wk
    cv.src[5] = (const float*)d_in[4];  cv.dst[5] = Wc2;  // Wv
    cv.src[6] = (const float*)d_in[10]; cv.dst[6] = Wc3;  // Wo
    prep<<<10240, 256, 0, stream>>>(cv, mask, maskw);

    GemmArgs g1;
    g1.X[0] = Xq;  g1.W[0] = Wc0; g1.B[0] = bq; g1.C[0] = qh; g1.scale[0] = QSCALE;
    g1.X[1] = Xv;  g1.W[1] = Wc2; g1.B[1] = bv; g1.C[1] = vh; g1.scale[1] = 1.f;
    g1.X[2] = Wc1; g1.W[2] = Xk;  g1.B[2] = bk; g1.C[2] = kt; g1.scale[2] = 1.f;  // transposed K
    gemm_bt<0><<<dim3(32, 8, 3), 256, 0, stream>>>(g1);

    attn4<<<dim3(16, 32, 2), 256, 0, stream>>>(qh, vh, kt, maskw, Opart, lpart);

    combine<<<2048, 256, 0, stream>>>(Opart, lpart, attr);

    gemm1_64<<<dim3(32, 16), 256, 0, stream>>>(attr, Wc3, bo, out);
}